// Round 3
// baseline (43.066 us; speedup 1.0000x reference)
//
#include <hip/hip_runtime.h>
#include <hip/hip_bf16.h>

// Problem constants: (8, 2048, 128) fp32 x2 -> (8, 2048, 2048) fp32
#define BATCH 8
#define RROWS 2048
#define DDIM  128
#define BM    128
#define BN    128
#define NROWS (BATCH * RROWS)           // rows per matrix
#define WS_BYTES_PER_MAT ((size_t)NROWS * DDIM * 2)   // bf16

using f32x4 = __attribute__((ext_vector_type(4))) float;
using s16x8 = __attribute__((ext_vector_type(8))) short;
using u16x4 = __attribute__((ext_vector_type(4))) unsigned short;

// fp32 -> bf16 round-to-nearest-even (inputs are finite normals)
__device__ __forceinline__ unsigned short f2bf(float f) {
    unsigned int u = __builtin_bit_cast(unsigned int, f);
    u += 0x7fffu + ((u >> 16) & 1u);
    return (unsigned short)(u >> 16);
}

// ---------------- Kernel 1: L2-normalize rows of both matrices -> bf16 in ws ----------------
__global__ __launch_bounds__(256) void normalize_kernel(const float* __restrict__ m1,
                                                        const float* __restrict__ m2,
                                                        unsigned short* __restrict__ wsA,
                                                        unsigned short* __restrict__ wsB) {
    const int tid    = threadIdx.x;
    const int lane32 = tid & 31;
    const int row    = (blockIdx.x * 256 + tid) >> 5;   // one row per 32-lane group
    if (row >= NROWS) return;

    const size_t off = (size_t)row * DDIM + lane32 * 4;

    const float4 va = *(const float4*)(m1 + off);
    const float4 vb = *(const float4*)(m2 + off);
    float sa = va.x * va.x + va.y * va.y + va.z * va.z + va.w * va.w;
    float sb = vb.x * vb.x + vb.y * vb.y + vb.z * vb.z + vb.w * vb.w;
    #pragma unroll
    for (int s = 1; s <= 16; s <<= 1) {
        sa += __shfl_xor(sa, s);
        sb += __shfl_xor(sb, s);
    }
    const float ia = rsqrtf(fmaxf(sa, 1e-8f));
    const float ib = rsqrtf(fmaxf(sb, 1e-8f));

    u16x4 pa, pb;
    pa[0] = f2bf(va.x * ia); pa[1] = f2bf(va.y * ia);
    pa[2] = f2bf(va.z * ia); pa[3] = f2bf(va.w * ia);
    pb[0] = f2bf(vb.x * ib); pb[1] = f2bf(vb.y * ib);
    pb[2] = f2bf(vb.z * ib); pb[3] = f2bf(vb.w * ib);
    *(u16x4*)(wsA + off) = pa;
    *(u16x4*)(wsB + off) = pb;
}

// ---------------- Kernel 2: bf16 GEMM, gload_lds staging + LDS-transposed float4 epilogue ----------------
__global__ __launch_bounds__(256, 2) void gemm_kernel(const unsigned short* __restrict__ wsA,
                                                      const unsigned short* __restrict__ wsB,
                                                      float* __restrict__ out) {
    __shared__ __align__(16) char lds[BM * DDIM * 2 + BN * DDIM * 2];  // 64 KiB
    char* As = lds;
    char* Bs = lds + BM * DDIM * 2;

    const int tid    = threadIdx.x;
    const int b      = blockIdx.z;
    const int tile_m = blockIdx.y;
    const int tile_n = blockIdx.x;
    const int wave   = tid >> 6;
    const int lane   = tid & 63;

    const char* gA = (const char*)(wsA + ((size_t)b * RROWS + (size_t)tile_m * BM) * DDIM);
    const char* gB = (const char*)(wsB + ((size_t)b * RROWS + (size_t)tile_n * BN) * DDIM);

    // Stage panels: 32 KiB each. LDS dest is linear (wave-uniform base + lane*16);
    // the XOR-swizzle is applied by reading the INVERSE-swizzled global address
    // per lane (the swizzle is an involution).
    #pragma unroll
    for (int it = 0; it < 8; ++it) {
        const int chunk = (wave * 8 + it) * 1024;
        const int L  = chunk + lane * 16;
        const int gl = L ^ (((L >> 8) & 7) << 4);
        __builtin_amdgcn_global_load_lds((const __attribute__((address_space(1))) void*)(gA + gl),
                                         (__attribute__((address_space(3))) void*)(As + chunk), 16, 0, 0);
        __builtin_amdgcn_global_load_lds((const __attribute__((address_space(1))) void*)(gB + gl),
                                         (__attribute__((address_space(3))) void*)(Bs + chunk), 16, 0, 0);
    }
    __syncthreads();

    // 4 waves in 2x2, each computes a 64x64 sub-tile
    const int wr   = wave >> 1;
    const int wc   = wave & 1;
    const int lrow = lane & 15;
    const int kb   = (lane >> 4) * 8;

    f32x4 acc[4][4];
    #pragma unroll
    for (int m = 0; m < 4; ++m)
        #pragma unroll
        for (int n = 0; n < 4; ++n)
            acc[m][n] = f32x4{0.f, 0.f, 0.f, 0.f};

    #pragma unroll
    for (int kk = 0; kk < 4; ++kk) {
        const int k = kk * 32 + kb;
        s16x8 af[4], bfr[4];
        #pragma unroll
        for (int m = 0; m < 4; ++m) {
            const int ra   = wr * 64 + m * 16 + lrow;
            const int offa = ra * 256 + k * 2;
            af[m] = *(const s16x8*)(As + (offa ^ ((ra & 7) << 4)));
            const int rb   = wc * 64 + m * 16 + lrow;
            const int offb = rb * 256 + k * 2;
            bfr[m] = *(const s16x8*)(Bs + (offb ^ ((rb & 7) << 4)));
        }
        #pragma unroll
        for (int m = 0; m < 4; ++m)
            #pragma unroll
            for (int n = 0; n < 4; ++n)
                acc[m][n] = __builtin_amdgcn_mfma_f32_16x16x32_bf16(af[m], bfr[n], acc[m][n], 0, 0, 0);
    }

    // ---- Epilogue: transpose C tile through LDS (panels are dead), float4 stores ----
    __syncthreads();                       // all panel reads complete before overwrite
    char* Cs = lds;                        // 128 rows x 128 f32 = 64 KiB, XOR-swizzled

    // C/D layout: col = lane&15, row = (lane>>4)*4 + reg.
    // Swizzle byte^((row&7)<<4): lane-groups at rows r,r+4 -> disjoint banks (bit6
    // of byte flips); worst residual is 2-way (free, m136).
    const int crow0 = wr * 64 + (lane >> 4) * 4;
    const int ccol0 = wc * 64 + lrow;
    #pragma unroll
    for (int m = 0; m < 4; ++m) {
        #pragma unroll
        for (int n = 0; n < 4; ++n) {
            #pragma unroll
            for (int reg = 0; reg < 4; ++reg) {
                const int row = crow0 + m * 16 + reg;
                const int col = ccol0 + n * 16;
                const int byteoff = row * 512 + col * 4;
                *(float*)(Cs + (byteoff ^ ((row & 7) << 4))) = acc[m][n][reg];
            }
        }
    }
    __syncthreads();

    // Read back rows, store contiguous 1 KiB per wave-instruction (nontemporal:
    // output is write-once, never re-read).
    float* gout = out + (size_t)b * RROWS * RROWS
                      + (size_t)(tile_m * BM) * RROWS + tile_n * BN;
    #pragma unroll
    for (int it = 0; it < 16; ++it) {
        const int idx = it * 256 + tid;    // float4 index within the 128x128 tile
        const int row = idx >> 5;          // 32 float4 per row
        const int c4  = idx & 31;
        const int byteoff = row * 512 + c4 * 16;
        const f32x4 v = *(const f32x4*)(Cs + (byteoff ^ ((row & 7) << 4)));
        __builtin_nontemporal_store(v, (f32x4*)(gout + (size_t)row * RROWS + c4 * 4));
    }
}

extern "C" void kernel_launch(void* const* d_in, const int* in_sizes, int n_in,
                              void* d_out, int out_size, void* d_ws, size_t ws_size,
                              hipStream_t stream) {
    (void)in_sizes; (void)n_in; (void)out_size; (void)ws_size;
    const float* m1 = (const float*)d_in[0];
    const float* m2 = (const float*)d_in[1];
    float* out = (float*)d_out;

    unsigned short* wsA = (unsigned short*)d_ws;
    unsigned short* wsB = wsA + (size_t)NROWS * DDIM;
    normalize_kernel<<<dim3(NROWS / 8), dim3(256), 0, stream>>>(m1, m2, wsA, wsB);
    dim3 grid(RROWS / BN, RROWS / BM, BATCH);
    gemm_kernel<<<grid, dim3(256), 0, stream>>>(wsA, wsB, out);
}

// Round 4
// 41.050 us; speedup vs baseline: 1.0491x; 1.0491x over previous
//
#include <hip/hip_runtime.h>
#include <hip/hip_bf16.h>

// Problem constants: (8, 2048, 128) fp32 x2 -> (8, 2048, 2048) fp32
#define BATCH 8
#define RROWS 2048
#define DDIM  128
#define BM    128
#define BN    128
#define NROWS (BATCH * RROWS)           // rows per matrix
#define WS_BYTES_PER_MAT ((size_t)NROWS * DDIM * 2)   // bf16

using f32x4 = __attribute__((ext_vector_type(4))) float;
using s16x8 = __attribute__((ext_vector_type(8))) short;
using u16x4 = __attribute__((ext_vector_type(4))) unsigned short;

// fp32 -> bf16 round-to-nearest-even (inputs are finite normals)
__device__ __forceinline__ unsigned short f2bf(float f) {
    unsigned int u = __builtin_bit_cast(unsigned int, f);
    u += 0x7fffu + ((u >> 16) & 1u);
    return (unsigned short)(u >> 16);
}

// ---------------- Kernel 1: L2-normalize rows of both matrices -> bf16 in ws ----------------
__global__ __launch_bounds__(256) void normalize_kernel(const float* __restrict__ m1,
                                                        const float* __restrict__ m2,
                                                        unsigned short* __restrict__ wsA,
                                                        unsigned short* __restrict__ wsB) {
    const int tid    = threadIdx.x;
    const int lane32 = tid & 31;
    const int row    = (blockIdx.x * 256 + tid) >> 5;   // one row per 32-lane group
    if (row >= NROWS) return;

    const size_t off = (size_t)row * DDIM + lane32 * 4;

    const float4 va = *(const float4*)(m1 + off);
    const float4 vb = *(const float4*)(m2 + off);
    float sa = va.x * va.x + va.y * va.y + va.z * va.z + va.w * va.w;
    float sb = vb.x * vb.x + vb.y * vb.y + vb.z * vb.z + vb.w * vb.w;
    #pragma unroll
    for (int s = 1; s <= 16; s <<= 1) {
        sa += __shfl_xor(sa, s);
        sb += __shfl_xor(sb, s);
    }
    const float ia = rsqrtf(fmaxf(sa, 1e-8f));
    const float ib = rsqrtf(fmaxf(sb, 1e-8f));

    u16x4 pa, pb;
    pa[0] = f2bf(va.x * ia); pa[1] = f2bf(va.y * ia);
    pa[2] = f2bf(va.z * ia); pa[3] = f2bf(va.w * ia);
    pb[0] = f2bf(vb.x * ib); pb[1] = f2bf(vb.y * ib);
    pb[2] = f2bf(vb.z * ib); pb[3] = f2bf(vb.w * ib);
    *(u16x4*)(wsA + off) = pa;
    *(u16x4*)(wsB + off) = pb;
}

// ---------------- Kernel 2: bf16 GEMM, XCD-partitioned (batch per XCD) ----------------
// 1-D grid of 2048 blocks. lid%8 selects the XCD (round-robin dispatch), and we
// bind batch==XCD: each XCD touches only its own batch's panels (1.05 MB bf16),
// which stay resident in that XCD's 4 MB L2. All 16x panel re-reads become L2
// hits; HBM carries only output writes + cold panel reads.
__global__ __launch_bounds__(256, 2) void gemm_kernel(const unsigned short* __restrict__ wsA,
                                                      const unsigned short* __restrict__ wsB,
                                                      float* __restrict__ out) {
    __shared__ __align__(16) char lds[BM * DDIM * 2 + BN * DDIM * 2];  // 64 KiB
    char* As = lds;
    char* Bs = lds + BM * DDIM * 2;

    const int tid    = threadIdx.x;
    const int lid    = blockIdx.x;
    const int b      = lid & 7;            // batch == XCD
    const int idx    = lid >> 3;           // 0..255 within XCD
    const int tile_m = idx >> 4;
    const int tile_n = idx & 15;           // n fastest: A panel reused by consecutive blocks
    const int wave   = tid >> 6;
    const int lane   = tid & 63;

    const char* gA = (const char*)(wsA + ((size_t)b * RROWS + (size_t)tile_m * BM) * DDIM);
    const char* gB = (const char*)(wsB + ((size_t)b * RROWS + (size_t)tile_n * BN) * DDIM);

    // Stage panels: 32 KiB each. LDS dest is linear (wave-uniform base + lane*16);
    // the XOR-swizzle is applied by reading the INVERSE-swizzled global address
    // per lane (the swizzle is an involution).
    #pragma unroll
    for (int it = 0; it < 8; ++it) {
        const int chunk = (wave * 8 + it) * 1024;
        const int L  = chunk + lane * 16;
        const int gl = L ^ (((L >> 8) & 7) << 4);
        __builtin_amdgcn_global_load_lds((const __attribute__((address_space(1))) void*)(gA + gl),
                                         (__attribute__((address_space(3))) void*)(As + chunk), 16, 0, 0);
        __builtin_amdgcn_global_load_lds((const __attribute__((address_space(1))) void*)(gB + gl),
                                         (__attribute__((address_space(3))) void*)(Bs + chunk), 16, 0, 0);
    }
    __syncthreads();

    // 4 waves in 2x2, each computes a 64x64 sub-tile
    const int wr   = wave >> 1;
    const int wc   = wave & 1;
    const int lrow = lane & 15;
    const int kb   = (lane >> 4) * 8;

    f32x4 acc[4][4];
    #pragma unroll
    for (int m = 0; m < 4; ++m)
        #pragma unroll
        for (int n = 0; n < 4; ++n)
            acc[m][n] = f32x4{0.f, 0.f, 0.f, 0.f};

    #pragma unroll
    for (int kk = 0; kk < 4; ++kk) {
        const int k = kk * 32 + kb;
        s16x8 af[4], bfr[4];
        #pragma unroll
        for (int m = 0; m < 4; ++m) {
            const int ra   = wr * 64 + m * 16 + lrow;
            const int offa = ra * 256 + k * 2;
            af[m] = *(const s16x8*)(As + (offa ^ ((ra & 7) << 4)));
            const int rb   = wc * 64 + m * 16 + lrow;
            const int offb = rb * 256 + k * 2;
            bfr[m] = *(const s16x8*)(Bs + (offb ^ ((rb & 7) << 4)));
        }
        #pragma unroll
        for (int m = 0; m < 4; ++m)
            #pragma unroll
            for (int n = 0; n < 4; ++n)
                acc[m][n] = __builtin_amdgcn_mfma_f32_16x16x32_bf16(af[m], bfr[n], acc[m][n], 0, 0, 0);
    }

    // ---- Epilogue: transpose C tile through LDS (panels are dead), float4 nt stores ----
    __syncthreads();                       // all panel reads complete before overwrite
    char* Cs = lds;                        // 128 rows x 128 f32 = 64 KiB, XOR-swizzled

    const int crow0 = wr * 64 + (lane >> 4) * 4;
    const int ccol0 = wc * 64 + lrow;
    #pragma unroll
    for (int m = 0; m < 4; ++m) {
        #pragma unroll
        for (int n = 0; n < 4; ++n) {
            #pragma unroll
            for (int reg = 0; reg < 4; ++reg) {
                const int row = crow0 + m * 16 + reg;
                const int col = ccol0 + n * 16;
                const int byteoff = row * 512 + col * 4;
                *(float*)(Cs + (byteoff ^ ((row & 7) << 4))) = acc[m][n][reg];
            }
        }
    }
    __syncthreads();

    // Contiguous 1 KiB per wave-instruction, nontemporal (write-once stream;
    // also keeps the hot panel set resident in the XCD L2).
    float* gout = out + (size_t)b * RROWS * RROWS
                      + (size_t)(tile_m * BM) * RROWS + tile_n * BN;
    #pragma unroll
    for (int it = 0; it < 16; ++it) {
        const int idx4 = it * 256 + tid;   // float4 index within the 128x128 tile
        const int row  = idx4 >> 5;        // 32 float4 per row
        const int c4   = idx4 & 31;
        const int byteoff = row * 512 + c4 * 16;
        const f32x4 v = *(const f32x4*)(Cs + (byteoff ^ ((row & 7) << 4)));
        __builtin_nontemporal_store(v, (f32x4*)(gout + (size_t)row * RROWS + c4 * 4));
    }
}

extern "C" void kernel_launch(void* const* d_in, const int* in_sizes, int n_in,
                              void* d_out, int out_size, void* d_ws, size_t ws_size,
                              hipStream_t stream) {
    (void)in_sizes; (void)n_in; (void)out_size; (void)ws_size;
    const float* m1 = (const float*)d_in[0];
    const float* m2 = (const float*)d_in[1];
    float* out = (float*)d_out;

    unsigned short* wsA = (unsigned short*)d_ws;
    unsigned short* wsB = wsA + (size_t)NROWS * DDIM;
    normalize_kernel<<<dim3(NROWS / 8), dim3(256), 0, stream>>>(m1, m2, wsA, wsB);
    gemm_kernel<<<dim3(BATCH * (RROWS / BM) * (RROWS / BN)), dim3(256), 0, stream>>>(wsA, wsB, out);
}

// Round 5
// 35.037 us; speedup vs baseline: 1.2292x; 1.1716x over previous
//
#include <hip/hip_runtime.h>
#include <hip/hip_bf16.h>

// Problem constants: (8, 2048, 128) fp32 x2 -> (8, 2048, 2048) fp32
#define BATCH 8
#define RROWS 2048
#define DDIM  128
#define BM    128
#define BN    64
#define NROWS (BATCH * RROWS)

using f32x4 = __attribute__((ext_vector_type(4))) float;
using s16x8 = __attribute__((ext_vector_type(8))) short;
using u16x4 = __attribute__((ext_vector_type(4))) unsigned short;

#define WAITVM(N) asm volatile("s_waitcnt vmcnt(" #N ")" ::: "memory")
#define SCHED0()  __builtin_amdgcn_sched_barrier(0)

#define GLL16(src, dst)                                                          \
    __builtin_amdgcn_global_load_lds(                                            \
        (const __attribute__((address_space(1))) void*)(src),                    \
        (__attribute__((address_space(3))) void*)(dst), 16, 0, 0)

// fp32 -> bf16 round-to-nearest-even (inputs are finite normals)
__device__ __forceinline__ unsigned short f2bf(float f) {
    unsigned int u = __builtin_bit_cast(unsigned int, f);
    u += 0x7fffu + ((u >> 16) & 1u);
    return (unsigned short)(u >> 16);
}

// ---------------- Kernel 1: L2-normalize rows of both matrices -> bf16 in ws ----------------
__global__ __launch_bounds__(256) void normalize_kernel(const float* __restrict__ m1,
                                                        const float* __restrict__ m2,
                                                        unsigned short* __restrict__ wsA,
                                                        unsigned short* __restrict__ wsB) {
    const int tid    = threadIdx.x;
    const int lane32 = tid & 31;
    const int row    = (blockIdx.x * 256 + tid) >> 5;
    if (row >= NROWS) return;

    const size_t off = (size_t)row * DDIM + lane32 * 4;

    const float4 va = *(const float4*)(m1 + off);
    const float4 vb = *(const float4*)(m2 + off);
    float sa = va.x * va.x + va.y * va.y + va.z * va.z + va.w * va.w;
    float sb = vb.x * vb.x + vb.y * vb.y + vb.z * vb.z + vb.w * vb.w;
    #pragma unroll
    for (int s = 1; s <= 16; s <<= 1) {
        sa += __shfl_xor(sa, s);
        sb += __shfl_xor(sb, s);
    }
    const float ia = rsqrtf(fmaxf(sa, 1e-8f));
    const float ib = rsqrtf(fmaxf(sb, 1e-8f));

    u16x4 pa, pb;
    pa[0] = f2bf(va.x * ia); pa[1] = f2bf(va.y * ia);
    pa[2] = f2bf(va.z * ia); pa[3] = f2bf(va.w * ia);
    pb[0] = f2bf(vb.x * ib); pb[1] = f2bf(vb.y * ib);
    pb[2] = f2bf(vb.z * ib); pb[3] = f2bf(vb.w * ib);
    *(u16x4*)(wsA + off) = pa;
    *(u16x4*)(wsB + off) = pb;
}

// ---------------- Kernel 2: persistent-tile bf16 GEMM, counted-vmcnt pipeline ----------------
// Grid 512, 1-D. lid&7 = batch = XCD (panels L2-resident per XCD). Each block
// owns (batch, tile_m, n-quarter) and iterates 8 tiles of 128x64: A staged once,
// B double-buffered; raw s_barrier + counted vmcnt keeps the store queue full
// across tile boundaries (no vmcnt(0) drain until wave retire).
__global__ __launch_bounds__(256, 2) void gemm_kernel(const unsigned short* __restrict__ wsA,
                                                      const unsigned short* __restrict__ wsB,
                                                      float* __restrict__ out) {
    __shared__ __align__(16) char lds[32768 + 2 * 16384];   // A 32K + B dbuf 2x16K
    char* As  = lds;
    char* Bs0 = lds + 32768;
    char* Bs1 = lds + 49152;

    const int tid    = threadIdx.x;
    const int wave   = tid >> 6;
    const int lane   = tid & 63;
    const int lid    = blockIdx.x;
    const int b      = lid & 7;            // batch == XCD
    const int idx    = lid >> 3;           // 0..63
    const int tile_m = idx >> 2;           // 0..15
    const int q      = idx & 3;            // n-quarter: tiles q*8 .. q*8+7

    const char* gA  = (const char*)(wsA + ((size_t)b * RROWS + (size_t)tile_m * BM) * DDIM);
    const char* gB0 = (const char*)(wsB + ((size_t)b * RROWS + (size_t)q * 512) * DDIM);

    // Prologue: stage A (32KB, 8 issues/wave) + B0 (16KB, 4 issues/wave).
    // LDS dest linear; XOR-swizzle applied via inverse-swizzled global source.
    #pragma unroll
    for (int it = 0; it < 8; ++it) {
        const int chunk = (wave * 8 + it) * 1024;
        const int L  = chunk + lane * 16;
        const int gl = L ^ (((L >> 8) & 7) << 4);
        GLL16(gA + gl, As + chunk);
    }
    #pragma unroll
    for (int it = 0; it < 4; ++it) {
        const int chunk = (wave * 4 + it) * 1024;
        const int L  = chunk + lane * 16;
        const int gl = L ^ (((L >> 8) & 7) << 4);
        GLL16(gB0 + gl, Bs0 + chunk);
    }

    const int wr   = wave >> 1;            // 0..1 : row half (64 rows)
    const int wc   = wave & 1;             // 0..1 : col half (32 cols)
    const int lrow = lane & 15;
    const int kb   = (lane >> 4) * 8;

    float* gout_base = out + (size_t)b * RROWS * RROWS
                           + (size_t)(tile_m * BM) * RROWS + (size_t)q * 512;

    #pragma unroll
    for (int t = 0; t < 8; ++t) {
        // P0: issue next B stage (async; dest buffer freed by last iter's barrier)
        SCHED0();
        if (t < 7) {
            const char* gb = gB0 + (t + 1) * 16384;
            char* bd = ((t + 1) & 1) ? Bs1 : Bs0;
            #pragma unroll
            for (int it = 0; it < 4; ++it) {
                const int chunk = (wave * 4 + it) * 1024;
                const int L  = chunk + lane * 16;
                const int gl = L ^ (((L >> 8) & 7) << 4);
                GLL16(gb + gl, bd + chunk);
            }
        }
        SCHED0();
        // P1: counted wait — B(t) loads confirmed, older stores may stay in flight.
        // FIFO per wave/iter: 4 B-loads then 32 stores. Newest-after-B(t):
        //   t==0: B1(4)=4;  t==7: stores(6)=32;  else: stores(t-1)+B(t+1)=36.
        if (t == 0)      WAITVM(4);
        else if (t == 7) WAITVM(32);
        else             WAITVM(36);
        SCHED0();
        __builtin_amdgcn_s_barrier();
        SCHED0();

        // P2: MFMA from As + Bs[t&1]
        const char* Bs = (t & 1) ? Bs1 : Bs0;
        f32x4 acc[4][2];
        #pragma unroll
        for (int m = 0; m < 4; ++m)
            #pragma unroll
            for (int n = 0; n < 2; ++n)
                acc[m][n] = f32x4{0.f, 0.f, 0.f, 0.f};

        #pragma unroll
        for (int kk = 0; kk < 4; ++kk) {
            const int k = kk * 32 + kb;
            s16x8 af[4], bfr[2];
            #pragma unroll
            for (int m = 0; m < 4; ++m) {
                const int ra   = wr * 64 + m * 16 + lrow;
                const int offa = ra * 256 + k * 2;
                af[m] = *(const s16x8*)(As + (offa ^ ((ra & 7) << 4)));
            }
            #pragma unroll
            for (int n = 0; n < 2; ++n) {
                const int rb   = wc * 32 + n * 16 + lrow;
                const int offb = rb * 256 + k * 2;
                bfr[n] = *(const s16x8*)(Bs + (offb ^ ((rb & 7) << 4)));
            }
            #pragma unroll
            for (int m = 0; m < 4; ++m)
                #pragma unroll
                for (int n = 0; n < 2; ++n)
                    acc[m][n] = __builtin_amdgcn_mfma_f32_16x16x32_bf16(af[m], bfr[n], acc[m][n], 0, 0, 0);
        }

        // Stores: direct from regs (plain — 64B segments write-combine in L2).
        // C/D layout: col = lane&15, row = (lane>>4)*4 + reg.
        float* gout = gout_base + t * BN;
        const int orow0 = wr * 64 + (lane >> 4) * 4;
        const int ocol0 = wc * 32 + lrow;
        #pragma unroll
        for (int m = 0; m < 4; ++m) {
            #pragma unroll
            for (int n = 0; n < 2; ++n) {
                const int col = ocol0 + n * 16;
                #pragma unroll
                for (int reg = 0; reg < 4; ++reg) {
                    const int row = orow0 + m * 16 + reg;
                    gout[(size_t)row * RROWS + col] = acc[m][n][reg];
                }
            }
        }

        // P3: all waves done reading Bs[t&1] before next iter overwrites it.
        SCHED0();
        __builtin_amdgcn_s_barrier();
        SCHED0();
    }
}

extern "C" void kernel_launch(void* const* d_in, const int* in_sizes, int n_in,
                              void* d_out, int out_size, void* d_ws, size_t ws_size,
                              hipStream_t stream) {
    (void)in_sizes; (void)n_in; (void)out_size; (void)ws_size;
    const float* m1 = (const float*)d_in[0];
    const float* m2 = (const float*)d_in[1];
    float* out = (float*)d_out;

    unsigned short* wsA = (unsigned short*)d_ws;
    unsigned short* wsB = wsA + (size_t)NROWS * DDIM;
    normalize_kernel<<<dim3(NROWS / 8), dim3(256), 0, stream>>>(m1, m2, wsA, wsB);
    gemm_kernel<<<dim3(512), dim3(256), 0, stream>>>(wsA, wsB, out);
}

// Round 6
// 33.126 us; speedup vs baseline: 1.3001x; 1.0577x over previous
//
#include <hip/hip_runtime.h>
#include <hip/hip_bf16.h>

// Problem constants: (8, 2048, 128) fp32 x2 -> (8, 2048, 2048) fp32
#define BATCH 8
#define RROWS 2048
#define DDIM  128
#define BM    128
#define BN    64

using f32x4 = __attribute__((ext_vector_type(4))) float;
using s16x8 = __attribute__((ext_vector_type(8))) short;
using u16x4 = __attribute__((ext_vector_type(4))) unsigned short;

#define SCHED0() __builtin_amdgcn_sched_barrier(0)
#define LGKM0()  asm volatile("s_waitcnt lgkmcnt(0)" ::: "memory")

// fp32 -> bf16 round-to-nearest-even (inputs are finite normals)
__device__ __forceinline__ unsigned short f2bf(float f) {
    unsigned int u = __builtin_bit_cast(unsigned int, f);
    u += 0x7fffu + ((u >> 16) & 1u);
    return (unsigned short)(u >> 16);
}

// One lane's float4 slice of a 32-lane row -> L2-normalized bf16 quad.
// (sum across the owning 32-lane group; deterministic across blocks)
__device__ __forceinline__ u16x4 norm_cvt(float4 v) {
    float s = v.x * v.x + v.y * v.y + v.z * v.z + v.w * v.w;
    #pragma unroll
    for (int i = 1; i <= 16; i <<= 1) s += __shfl_xor(s, i);
    const float r = rsqrtf(fmaxf(s, 1e-8f));
    u16x4 p;
    p[0] = f2bf(v.x * r); p[1] = f2bf(v.y * r);
    p[2] = f2bf(v.z * r); p[3] = f2bf(v.w * r);
    return p;
}

// ---------------- Fused persistent-tile kernel ----------------
// Grid 512. lid&7 = batch = XCD (inputs 2.1 MB fp32 per batch stay L2-resident).
// Each block: normalize its A panel (128 rows) once into LDS; loop 8 B-tiles of
// 64 rows with a 1-deep register prefetch (fp32 loads issued one tile ahead;
// normalize+ds_write AFTER this tile's stores so the compiler's auto vmcnt wait
// for rb leaves the 32 stores in flight -> store queue never drains mid-kernel).
__global__ __launch_bounds__(256, 2) void fused_kernel(const float* __restrict__ m1,
                                                       const float* __restrict__ m2,
                                                       float* __restrict__ out) {
    __shared__ __align__(16) char lds[32768 + 2 * 16384];  // A 32K + B dbuf 2x16K
    char* As  = lds;
    char* Bs0 = lds + 32768;
    char* Bs1 = lds + 49152;

    const int tid    = threadIdx.x;
    const int wave   = tid >> 6;
    const int lane   = tid & 63;
    const int l32    = tid & 31;
    const int grp    = tid >> 5;           // 0..7 : row-group within a slab
    const int lid    = blockIdx.x;
    const int b      = lid & 7;            // batch == XCD
    const int idx    = lid >> 3;           // 0..63
    const int tile_m = idx >> 2;           // 0..15
    const int q      = idx & 3;            // n-quarter

    const float* gA = m1 + ((size_t)b * RROWS + (size_t)tile_m * BM) * DDIM;
    const float* gB = m2 + ((size_t)b * RROWS + (size_t)q * 512) * DDIM;

    // ---- Prologue ----
    // Issue B(0) fp32 loads first so their latency hides under A-normalize.
    float4 rb[8];
    #pragma unroll
    for (int i = 0; i < 8; ++i)
        rb[i] = *(const float4*)(gB + (size_t)(i * 8 + grp) * DDIM + l32 * 4);

    // Normalize A panel: 16 slabs x 8 rows. Swizzled LDS write (involution
    // matches the s16x8 read side).
    #pragma unroll
    for (int s = 0; s < 16; ++s) {
        const int r = s * 8 + grp;
        const float4 va = *(const float4*)(gA + (size_t)r * DDIM + l32 * 4);
        const u16x4 pa = norm_cvt(va);
        const int off = r * 256 + l32 * 8;
        *(u16x4*)(As + (off ^ ((r & 7) << 4))) = pa;
    }

    // Process B(0) -> Bs0, then prefetch B(1).
    #pragma unroll
    for (int i = 0; i < 8; ++i) {
        const int r = i * 8 + grp;
        const u16x4 pb = norm_cvt(rb[i]);
        const int off = r * 256 + l32 * 8;
        *(u16x4*)(Bs0 + (off ^ ((r & 7) << 4))) = pb;
    }
    #pragma unroll
    for (int i = 0; i < 8; ++i)
        rb[i] = *(const float4*)(gB + (size_t)(64 + i * 8 + grp) * DDIM + l32 * 4);

    LGKM0();
    __builtin_amdgcn_s_barrier();

    const int wr   = wave >> 1;            // 0..1 : 64-row half
    const int wc   = wave & 1;             // 0..1 : 32-col half
    const int lrow = lane & 15;
    const int kb   = (lane >> 4) * 8;

    float* gout_base = out + (size_t)b * RROWS * RROWS
                           + (size_t)(tile_m * BM) * RROWS + (size_t)q * 512;

    #pragma unroll
    for (int t = 0; t < 8; ++t) {
        const char* Bs  = (t & 1) ? Bs1 : Bs0;
        char*       Bsn = (t & 1) ? Bs0 : Bs1;

        // ---- MFMA from As + Bs[t&1] ----
        f32x4 acc[4][2];
        #pragma unroll
        for (int m = 0; m < 4; ++m)
            #pragma unroll
            for (int n = 0; n < 2; ++n)
                acc[m][n] = f32x4{0.f, 0.f, 0.f, 0.f};

        #pragma unroll
        for (int kk = 0; kk < 4; ++kk) {
            const int k = kk * 32 + kb;
            s16x8 af[4], bfr[2];
            #pragma unroll
            for (int m = 0; m < 4; ++m) {
                const int ra   = wr * 64 + m * 16 + lrow;
                const int offa = ra * 256 + k * 2;
                af[m] = *(const s16x8*)(As + (offa ^ ((ra & 7) << 4)));
            }
            #pragma unroll
            for (int n = 0; n < 2; ++n) {
                const int rbr  = wc * 32 + n * 16 + lrow;
                const int offb = rbr * 256 + k * 2;
                bfr[n] = *(const s16x8*)(Bs + (offb ^ ((rbr & 7) << 4)));
            }
            #pragma unroll
            for (int m = 0; m < 4; ++m)
                #pragma unroll
                for (int n = 0; n < 2; ++n)
                    acc[m][n] = __builtin_amdgcn_mfma_f32_16x16x32_bf16(af[m], bfr[n], acc[m][n], 0, 0, 0);
        }

        // ---- Stores (fire-and-forget; nothing below waits vmcnt(0)) ----
        // C/D layout: col = lane&15, row = (lane>>4)*4 + reg.
        float* gout = gout_base + t * BN;
        const int orow0 = wr * 64 + (lane >> 4) * 4;
        const int ocol0 = wc * 32 + lrow;
        #pragma unroll
        for (int m = 0; m < 4; ++m) {
            #pragma unroll
            for (int n = 0; n < 2; ++n) {
                const int col = ocol0 + n * 16;
                #pragma unroll
                for (int reg = 0; reg < 4; ++reg) {
                    const int row = orow0 + m * 16 + reg;
                    gout[(size_t)row * RROWS + col] = acc[m][n][reg];
                }
            }
        }

        if (t < 7) {
            // Pin the process phase AFTER the stores: the compiler's auto
            // s_waitcnt for rb then counts the 32 stores as "issued after"
            // and emits vmcnt(~39) -> stores stay in flight.
            SCHED0();
            // Process B(t+1) -> other buffer (readers of it finished at t-1).
            #pragma unroll
            for (int i = 0; i < 8; ++i) {
                const int r = i * 8 + grp;
                const u16x4 pb = norm_cvt(rb[i]);
                const int off = r * 256 + l32 * 8;
                *(u16x4*)(Bsn + (off ^ ((r & 7) << 4))) = pb;
            }
            // Prefetch B(t+2) fp32 into regs (XCD-L2 hit after first pass).
            if (t < 6) {
                #pragma unroll
                for (int i = 0; i < 8; ++i)
                    rb[i] = *(const float4*)(gB + (size_t)((t + 2) * 64 + i * 8 + grp) * DDIM + l32 * 4);
            }
            LGKM0();                        // publish ds_writes
            __builtin_amdgcn_s_barrier();
        }
    }
}

extern "C" void kernel_launch(void* const* d_in, const int* in_sizes, int n_in,
                              void* d_out, int out_size, void* d_ws, size_t ws_size,
                              hipStream_t stream) {
    (void)in_sizes; (void)n_in; (void)out_size; (void)d_ws; (void)ws_size;
    const float* m1 = (const float*)d_in[0];
    const float* m2 = (const float*)d_in[1];
    float* out = (float*)d_out;

    fused_kernel<<<dim3(BATCH * (RROWS / BM) * (RROWS / BN / 8)), dim3(256), 0, stream>>>(m1, m2, out);
}